// Round 18
// baseline (197.271 us; speedup 1.0000x reference)
//
#include <hip/hip_runtime.h>
#include <hip/hip_bf16.h>
#include <type_traits>

// Problem: B=2, T=2048, D_MODEL=2048, H=16, Hkv=4, hd=128.
// Outputs (fp32, concat): out[2,2048,2048] | k_roped[2,4,2048,128] | v[2,4,2048,128]
//
// Q/K columns inside the internal qkv buffer are stored PERMUTED (per-head
// 32-col blocks [0,2,1,3]) so the RoPE pair (d, d+64) = stored (c, c+32).
// QK^T is permutation-invariant (both sides permuted), attention unchanged.

typedef short  short8 __attribute__((ext_vector_type(8)));
typedef float  f32x4  __attribute__((ext_vector_type(4)));
typedef float  f32x16 __attribute__((ext_vector_type(16)));

#define AS1(p) ((__attribute__((address_space(1))) void*)(p))
#define AS3(p) ((__attribute__((address_space(3))) void*)(p))

static __device__ inline short bf_bits(float f) {
    __hip_bfloat16 h = __float2bfloat16(f);
    return *reinterpret_cast<short*>(&h);
}

// pack two f32 -> one u32 of 2x bf16, LOW half = first arg (key j even).
static __device__ inline unsigned pack2(float lo, float hi2) {
    return (unsigned)(unsigned short)bf_bits(lo)
         | ((unsigned)(unsigned short)bf_bits(hi2) << 16);
}

// ---------------- Fused prep: weight transposes + x conversion ----------------
__global__ void prep_kernel(
    const float* __restrict__ x,
    const float* __restrict__ Wq, const float* __restrict__ Wk,
    const float* __restrict__ Wv, const float* __restrict__ Wo,
    __hip_bfloat16* __restrict__ xb,
    __hip_bfloat16* __restrict__ WqkvT, __hip_bfloat16* __restrict__ WoT)
{
    const int nb = blockIdx.x;
    const int tx = threadIdx.x, ty = threadIdx.y;   // 32 x 8
    if (nb >= 160) {
        int bid2 = (nb - 160) * 64 + blockIdx.y;    // 0..8191
        int i = (bid2 * 256 + ty * 32 + tx) * 4;
        float4 v = *reinterpret_cast<const float4*>(x + i);
        ushort4 o;
        o.x = (unsigned short)bf_bits(v.x);
        o.y = (unsigned short)bf_bits(v.y);
        o.z = (unsigned short)bf_bits(v.z);
        o.w = (unsigned short)bf_bits(v.w);
        *reinterpret_cast<ushort4*>(reinterpret_cast<unsigned short*>(xb) + i) = o;
        return;
    }
    __shared__ float tile[32][33];
    const int k0 = blockIdx.y * 32;
    const float* W; int srcN, sn0, drow; __hip_bfloat16* dst;
    if (nb < 64) {
        int blk = nb & 3;
        int blk2 = ((blk & 1) << 1) | (blk >> 1);   // 0,2,1,3
        W = Wq; srcN = 2048; sn0 = nb * 32;
        dst = WqkvT; drow = ((nb >> 2) * 4 + blk2) * 32;
    } else if (nb < 80) {
        int i = nb - 64, blk = i & 3;
        int blk2 = ((blk & 1) << 1) | (blk >> 1);
        W = Wk; srcN = 512; sn0 = i * 32;
        dst = WqkvT; drow = 2048 + ((i >> 2) * 4 + blk2) * 32;
    } else if (nb < 96) {
        int i = nb - 80;
        W = Wv; srcN = 512; sn0 = i * 32;
        dst = WqkvT; drow = 2560 + i * 32;
    } else {
        int i = nb - 96;
        W = Wo; srcN = 2048; sn0 = i * 32;
        dst = WoT; drow = i * 32;
    }
#pragma unroll
    for (int i = 0; i < 32; i += 8)
        tile[ty + i][tx] = W[(size_t)(k0 + ty + i) * srcN + sn0 + tx];
    __syncthreads();
#pragma unroll
    for (int i = 0; i < 32; i += 8)
        dst[(size_t)(drow + ty + i) * 2048 + k0 + tx] = __float2bfloat16(tile[tx][ty + i]);
}

// XCD-aware block decode for 128^2 tiles.
static __device__ inline void xcd_decode(int bid, int M, int N, int& m0, int& n0)
{
    const int xcd = bid & 7;
    const int idx = bid >> 3;
    const int mpx = (M >> 7) >> 3;
    const int rem = idx % (mpx * 4);
    const int mb = xcd * mpx + rem % mpx;
    const int nb = (idx / (mpx * 4)) * 4 + rem / mpx;
    m0 = mb << 7;
    n0 = nb << 7;
}

// Counted waits (T4): never drain to 0 in the main loop.
#define WAITV4 asm volatile("s_waitcnt vmcnt(4)" ::: "memory")
#define WAITV0 asm volatile("s_waitcnt vmcnt(0)" ::: "memory")

// ---------------- Wo GEMM: C[M][N] = A[M][K] * BT[N][K]^T ----------------
// 128x128 tile, 4 waves (2x2 of 64x64), BK=64, 2-phase double-buffered LDS,
// XOR-swizzled staging, 32x32x16 MFMA, XCD decode, T5 setprio on MFMA.
template <typename CT>
__global__ __launch_bounds__(256) void gemm_bt_kernel(
    const __hip_bfloat16* __restrict__ A,
    const __hip_bfloat16* __restrict__ BT,
    CT* __restrict__ C, int M, int N, int K)
{
    const int tid  = threadIdx.x;
    const int w    = tid >> 6;
    const int lane = tid & 63;
    const int l31  = lane & 31;
    const int hi   = lane >> 5;
    int m0, n0;
    xcd_decode(blockIdx.x, M, N, m0, n0);
    const int wm = (w >> 1) << 6;
    const int wn = (w & 1) << 6;

    __shared__ __hip_bfloat16 As[2][128 * 64];   // 32 KB
    __shared__ __hip_bfloat16 Bs[2][128 * 64];   // 32 KB

    f32x16 acc[2][2] = {};

#define GSTAGE(buf, k0_)                                                            \
    {                                                                               \
        _Pragma("unroll")                                                           \
        for (int i = 0; i < 4; ++i) {                                               \
            int c = tid + i * 256;                                                  \
            int row = c >> 3;                                                       \
            int soct = (c & 7) ^ (row & 7);                                         \
            const __hip_bfloat16* ga = A  + (size_t)(m0 + row) * K + (k0_) + soct * 8; \
            const __hip_bfloat16* gb = BT + (size_t)(n0 + row) * K + (k0_) + soct * 8; \
            __builtin_amdgcn_global_load_lds(AS1(ga), AS3(&As[buf][c * 8]), 16, 0, 0); \
            __builtin_amdgcn_global_load_lds(AS1(gb), AS3(&Bs[buf][c * 8]), 16, 0, 0); \
        }                                                                           \
    }

    GSTAGE(0, 0);
    __syncthreads();
    int cur = 0;
    const int nk = K >> 6;

    for (int t = 0; t < nk; ++t) {
        if (t + 1 < nk) GSTAGE(cur ^ 1, (t + 1) << 6);

        __builtin_amdgcn_s_setprio(1);
#pragma unroll
        for (int ks = 0; ks < 4; ++ks) {
            const int oct = ((ks * 2 + hi) ^ (l31 & 7)) << 3;
            short8 a[2], b[2];
#pragma unroll
            for (int mi = 0; mi < 2; ++mi)
                a[mi] = *reinterpret_cast<const short8*>(
                    reinterpret_cast<const short*>(&As[cur][0]) + (wm + mi * 32 + l31) * 64 + oct);
#pragma unroll
            for (int ni = 0; ni < 2; ++ni)
                b[ni] = *reinterpret_cast<const short8*>(
                    reinterpret_cast<const short*>(&Bs[cur][0]) + (wn + ni * 32 + l31) * 64 + oct);
#pragma unroll
            for (int mi = 0; mi < 2; ++mi)
#pragma unroll
                for (int ni = 0; ni < 2; ++ni)
                    acc[mi][ni] = __builtin_amdgcn_mfma_f32_32x32x16_bf16(
                        a[mi], b[ni], acc[mi][ni], 0, 0, 0);
        }
        __builtin_amdgcn_s_setprio(0);
        __syncthreads();
        cur ^= 1;
    }
#undef GSTAGE

#pragma unroll
    for (int mi = 0; mi < 2; ++mi)
#pragma unroll
        for (int ni = 0; ni < 2; ++ni)
#pragma unroll
            for (int reg = 0; reg < 16; ++reg) {
                int row = m0 + wm + mi * 32 + (reg & 3) + 8 * (reg >> 2) + 4 * hi;
                int col = n0 + wn + ni * 32 + l31;
                float v = acc[mi][ni][reg];
                if constexpr (std::is_same<CT, float>::value)
                    C[(size_t)row * N + col] = v;
                else
                    C[(size_t)row * N + col] = __float2bfloat16(v);
            }
}

// ---------------- Fused QKV GEMM + RoPE + K/V write-out ----------------
// R12-proven: ring-3/BK=32/counted-vmcnt, 128^2 tile, 2x2 wave layout,
// T5 setprio around the ds_read+MFMA cluster.
__global__ __launch_bounds__(256) void gemm_qkv_fused(
    const __hip_bfloat16* __restrict__ A,    // xb [4096][2048]
    const __hip_bfloat16* __restrict__ BT,   // WqkvT [3072][2048] (Q/K perm)
    __hip_bfloat16* __restrict__ qkv,        // [4096][3072]
    float* __restrict__ outk,                // [2,4,2048,128]
    float* __restrict__ outv,                // [2,4,2048,128]
    __hip_bfloat16* __restrict__ VT)         // [8][128][2048]
{
    const int tid  = threadIdx.x;
    const int w    = tid >> 6;
    const int lane = tid & 63;
    const int l31  = lane & 31;
    const int hi   = lane >> 5;
    int m0, n0;
    xcd_decode(blockIdx.x, 4096, 3072, m0, n0);
    const int wm = (w >> 1) << 6;            // 2x2 waves of 64x64
    const int wn = (w & 1) << 6;
    const int K = 2048;

    __shared__ __hip_bfloat16 As[3][128 * 32];
    __shared__ __hip_bfloat16 Bs[3][128 * 32];

    f32x16 acc[2][2] = {};

#define GSTAGE(buf, k0_)                                                             \
    {                                                                                \
        _Pragma("unroll")                                                            \
        for (int i = 0; i < 2; ++i) {                                                \
            int c = tid + i * 256;                                                   \
            int row = c >> 2;                                                        \
            int soct = (c & 3) ^ ((row >> 1) & 3);                                   \
            const __hip_bfloat16* ga = A  + (size_t)(m0 + row) * K + (k0_) + soct * 8; \
            const __hip_bfloat16* gb = BT + (size_t)(n0 + row) * K + (k0_) + soct * 8; \
            __builtin_amdgcn_global_load_lds(AS1(ga), AS3(&As[buf][c * 8]), 16, 0, 0); \
            __builtin_amdgcn_global_load_lds(AS1(gb), AS3(&Bs[buf][c * 8]), 16, 0, 0); \
        }                                                                            \
    }

    const int nk = 64;
    GSTAGE(0, 0);
    GSTAGE(1, 32);
    int cur = 0, stg = 2;

    for (int t = 0; t < nk; ++t) {
        if (t == nk - 1) { WAITV0; } else { WAITV4; }
        __builtin_amdgcn_s_barrier();
        __builtin_amdgcn_sched_barrier(0);
        if (t + 2 < nk) GSTAGE(stg, (t + 2) << 5);

        __builtin_amdgcn_s_setprio(1);
#pragma unroll
        for (int ks = 0; ks < 2; ++ks) {
            short8 a[2], b[2];
#pragma unroll
            for (int mi = 0; mi < 2; ++mi) {
                int row = wm + mi * 32 + l31;
                a[mi] = *reinterpret_cast<const short8*>(
                    reinterpret_cast<const short*>(&As[cur][0])
                    + row * 32 + (((ks * 2 + hi) ^ ((row >> 1) & 3)) << 3));
            }
#pragma unroll
            for (int ni = 0; ni < 2; ++ni) {
                int row = wn + ni * 32 + l31;
                b[ni] = *reinterpret_cast<const short8*>(
                    reinterpret_cast<const short*>(&Bs[cur][0])
                    + row * 32 + (((ks * 2 + hi) ^ ((row >> 1) & 3)) << 3));
            }
#pragma unroll
            for (int mi = 0; mi < 2; ++mi)
#pragma unroll
                for (int ni = 0; ni < 2; ++ni)
                    acc[mi][ni] = __builtin_amdgcn_mfma_f32_32x32x16_bf16(
                        a[mi], b[ni], acc[mi][ni], 0, 0, 0);
        }
        __builtin_amdgcn_s_setprio(0);
        cur = (cur == 2) ? 0 : cur + 1;
        stg = (stg == 2) ? 0 : stg + 1;
    }
#undef GSTAGE

    const int hc = n0 >> 7;                  // head-chunk 0..23
    if (hc < 20) {
        const int c0 = wn + l31;
        const int d_lo = (wn ? 32 : 0) + l31;
        const float invf = exp2f((float)d_lo * -0.20762050593046f);
        const int kh = hc - 16;
#pragma unroll
        for (int mi = 0; mi < 2; ++mi)
#pragma unroll
            for (int reg = 0; reg < 16; ++reg) {
                int row = m0 + wm + mi * 32 + (reg & 3) + 8 * (reg >> 2) + 4 * hi;
                int b = row >> 11, t = row & 2047;
                float ang = (float)t * invf;
                float s = __sinf(ang), c = __cosf(ang);
                float x1 = acc[mi][0][reg], x2 = acc[mi][1][reg];
                float o1 = x1 * c - x2 * s;
                float o2 = x2 * c + x1 * s;
                __hip_bfloat16* q = qkv + (size_t)row * 3072 + hc * 128 + c0;
                q[0]  = __float2bfloat16(o1);
                q[32] = __float2bfloat16(o2);
                if (hc >= 16) {
                    float* ok = outk + (size_t)((b * 4 + kh) * 2048 + t) * 128 + d_lo;
                    ok[0]  = o1;
                    ok[64] = o2;
                }
            }
    } else {
        const int kh = hc - 20;
#pragma unroll
        for (int mi = 0; mi < 2; ++mi)
#pragma unroll
            for (int reg = 0; reg < 16; ++reg) {
                int row = m0 + wm + mi * 32 + (reg & 3) + 8 * (reg >> 2) + 4 * hi;
                int b = row >> 11, t = row & 2047;
#pragma unroll
                for (int ni = 0; ni < 2; ++ni) {
                    int d = wn + ni * 32 + l31;
                    float v = acc[mi][ni][reg];
                    outv[(size_t)((b * 4 + kh) * 2048 + t) * 128 + d] = v;
                    VT[(size_t)((b * 4 + kh) * 128 + d) * 2048 + t] = __float2bfloat16(v);
                }
            }
    }
}

// ---------------- Flash attention v11 (causal, GQA, in-register P) ----------------
// 4 waves x 32 q-rows, KVBLK=64, double-buffered K/V via global_load_lds.
// QK^T with SWAPPED operands: mfma_32x32x16(K, Q) -> D col(lane&31)=q,
// row((reg&3)+8(reg>>2)+4hi)=key. Softmax in-register (no max tracking).
// PV A-frag assembled with GUARANTEED-semantics primitives:
//   pack2 (bit ops, low=even key) + __shfl_xor(.,32) + per-half select.
// Lane (l31,hi) holds chunk keys {0-3,8-11}+4hi in w0..w3; A-frag needs
// hi=0 -> keys 0..7, hi=1 -> keys 8..15:
//   a0 = hi ? partner(w2) : w0 ; a1 = hi ? partner(w3) : w1
//   a2 = hi ? w2 : partner(w0) ; a3 = hi ? w3 : partner(w1)
// No P LDS buffer: 0 LDS writes, 32 b128 reads/wave-tile (was 36r+32w).
__global__ __launch_bounds__(256, 2) void attn_kernel(
    const __hip_bfloat16* __restrict__ qkv,
    const __hip_bfloat16* __restrict__ VT,
    __hip_bfloat16* __restrict__ outO)
{
    const int bh = blockIdx.x;          // b*16 + h
    const int b = bh >> 4, h = bh & 15;
    const int kh = h >> 2;
    const int yb = blockIdx.y;          // 0..15
    const int qblk = (yb < 8) ? (15 - yb) : (yb - 8);   // LPT pairing
    const int tid = threadIdx.x;
    const int w = tid >> 6;
    const int lane = tid & 63;
    const int l31 = lane & 31;
    const int hi = lane >> 5;
    const int qrow0 = qblk * 128 + w * 32;
    const int qg = qrow0 + l31;          // this lane's q row

    __shared__ short Ks[2][64 * 128];   // 32 KB  [key][d]   (swizzled octets)
    __shared__ short Vs[2][128 * 64];   // 32 KB  [d][key]   (swizzled octets)
    __shared__ float Ls[4][32];         // per-wave 1/l

    const short* qkvs = reinterpret_cast<const short*>(qkv);
    const size_t kbase = (size_t)b * 2048 * 3072 + 2048 + kh * 128;
    const short* vtb = reinterpret_cast<const short*>(VT) + (size_t)(b * 4 + kh) * 128 * 2048;

    // Q fragments (B-operand): col=q=l31, k = ss*16 + hi*8 + j
    short8 qf[8];
    {
        const short* qp = qkvs + (size_t)(b * 2048 + qg) * 3072 + h * 128 + hi * 8;
#pragma unroll
        for (int ss = 0; ss < 8; ++ss)
            qf[ss] = *reinterpret_cast<const short8*>(qp + ss * 16);
    }

    f32x16 o[4] = {};                   // o[jb]: col d=jb*32+l31, rows q per reg
    float lsum = 0.f;

    const float scl2 = 0.12752749545902973f;   // (1/sqrt(128)) * log2(e)
    const int ntiles = qblk * 2 + 2;

#define STAGE(buf, kb_)                                                              \
    {                                                                                \
        _Pragma("unroll")                                                            \
        for (int i = 0; i < 4; ++i) {                                                \
            int c = tid + i * 256;                                                   \
            int row = c >> 4, c16 = (c & 15) ^ (row & 7);                            \
            const short* src = qkvs + kbase + (size_t)((kb_) + row) * 3072 + c16 * 8;\
            __builtin_amdgcn_global_load_lds(AS1(src),                               \
                AS3(&Ks[buf][(w * 64 + i * 256) * 8]), 16, 0, 0);                    \
        }                                                                            \
        _Pragma("unroll")                                                            \
        for (int i = 0; i < 4; ++i) {                                                \
            int c = tid + i * 256;                                                   \
            int d = c >> 3, c8 = (c & 7) ^ (d & 7);                                  \
            const short* src = vtb + (size_t)d * 2048 + (kb_) + c8 * 8;              \
            __builtin_amdgcn_global_load_lds(AS1(src),                               \
                AS3(&Vs[buf][(w * 64 + i * 256) * 8]), 16, 0, 0);                    \
        }                                                                            \
    }

    // One 16-key chunk of PV: build A-frag in-register, 4 MFMA over d.
#define PVCHUNK(scv, kb2, ks2)                                                       \
    {                                                                                \
        unsigned pw0 = pack2((scv)[(ks2) * 8 + 0], (scv)[(ks2) * 8 + 1]);            \
        unsigned pw1 = pack2((scv)[(ks2) * 8 + 2], (scv)[(ks2) * 8 + 3]);            \
        unsigned pw2 = pack2((scv)[(ks2) * 8 + 4], (scv)[(ks2) * 8 + 5]);            \
        unsigned pw3 = pack2((scv)[(ks2) * 8 + 6], (scv)[(ks2) * 8 + 7]);            \
        unsigned s0 = (unsigned)__shfl_xor((int)pw0, 32);                            \
        unsigned s1 = (unsigned)__shfl_xor((int)pw1, 32);                            \
        unsigned s2 = (unsigned)__shfl_xor((int)pw2, 32);                            \
        unsigned s3 = (unsigned)__shfl_xor((int)pw3, 32);                            \
        int4 pi;                                                                     \
        pi.x = (int)(hi ? s2 : pw0);                                                 \
        pi.y = (int)(hi ? s3 : pw1);                                                 \
        pi.z = (int)(hi ? pw2 : s0);                                                 \
        pi.w = (int)(hi ? pw3 : s1);                                                 \
        short8 pa = *reinterpret_cast<short8*>(&pi);                                 \
        const int ob = (kb2) * 4 + (ks2) * 2 + hi;                                   \
        _Pragma("unroll")                                                            \
        for (int jb = 0; jb < 4; ++jb) {                                             \
            short8 vf = *reinterpret_cast<const short8*>(                            \
                &Vs[cur][(jb * 32 + l31) * 64 + ((ob ^ (l31 & 7)) << 3)]);           \
            o[jb] = __builtin_amdgcn_mfma_f32_32x32x16_bf16(pa, vf, o[jb], 0, 0, 0); \
        }                                                                            \
    }

    STAGE(0, 0);
    __syncthreads();
    int cur = 0;

    for (int t = 0; t < ntiles; ++t) {
        const int kb = t * 64;
        if (t + 1 < ntiles) STAGE(cur ^ 1, kb + 64);

        // ---- QK^T (swapped): sc0 = keys kb..kb+31, sc1 = kb+32..kb+63
        f32x16 sc0 = {}, sc1 = {};
        __builtin_amdgcn_s_setprio(1);
#pragma unroll
        for (int ss = 0; ss < 8; ++ss) {
            const int oct = ((ss * 2 + hi) ^ (l31 & 7)) << 3;
            short8 k0 = *reinterpret_cast<const short8*>(&Ks[cur][l31 * 128 + oct]);
            short8 k1 = *reinterpret_cast<const short8*>(&Ks[cur][(32 + l31) * 128 + oct]);
            sc0 = __builtin_amdgcn_mfma_f32_32x32x16_bf16(k0, qf[ss], sc0, 0, 0, 0);
            sc1 = __builtin_amdgcn_mfma_f32_32x32x16_bf16(k1, qf[ss], sc1, 0, 0, 0);
        }
        __builtin_amdgcn_s_setprio(0);

        // ---- scale + (mask) + exp2, in-register; accumulate lsum
        if (kb + 63 > qrow0) {
#pragma unroll
            for (int r = 0; r < 16; ++r) {
                int kl = (r & 3) + 8 * (r >> 2) + 4 * hi;
                float p0 = (kb + kl <= qg)
                         ? __builtin_amdgcn_exp2f(sc0[r] * scl2) : 0.f;
                float p1 = (kb + 32 + kl <= qg)
                         ? __builtin_amdgcn_exp2f(sc1[r] * scl2) : 0.f;
                sc0[r] = p0; sc1[r] = p1;
                lsum += p0 + p1;
            }
        } else {
#pragma unroll
            for (int r = 0; r < 16; ++r) {
                float p0 = __builtin_amdgcn_exp2f(sc0[r] * scl2);
                float p1 = __builtin_amdgcn_exp2f(sc1[r] * scl2);
                sc0[r] = p0; sc1[r] = p1;
                lsum += p0 + p1;
            }
        }

        // ---- PV: 4 chunks of 16 keys, A-frag in-register
        __builtin_amdgcn_s_setprio(1);
        PVCHUNK(sc0, 0, 0);
        PVCHUNK(sc0, 0, 1);
        PVCHUNK(sc1, 1, 0);
        PVCHUNK(sc1, 1, 1);
        __builtin_amdgcn_s_setprio(0);

        __syncthreads();   // stage writes drained + all reads of cur done
        cur ^= 1;
    }
#undef STAGE
#undef PVCHUNK

    // ---- finalize l: combine lane halves (keys split across hi), invert
    float lt = lsum + __shfl_xor(lsum, 32);
    if (hi == 0) Ls[w][l31] = 1.0f / lt;   // same-wave DS: in-order, no barrier

    float inv[16];
#pragma unroll
    for (int r = 0; r < 16; ++r)
        inv[r] = Ls[w][(r & 3) + 8 * (r >> 2) + 4 * hi];

#pragma unroll
    for (int jb = 0; jb < 4; ++jb)
#pragma unroll
        for (int r = 0; r < 16; ++r) {
            int qr = qrow0 + (r & 3) + 8 * (r >> 2) + 4 * hi;
            outO[(size_t)(b * 2048 + qr) * 2048 + h * 128 + jb * 32 + l31] =
                __float2bfloat16(o[jb][r] * inv[r]);
        }
}

extern "C" void kernel_launch(void* const* d_in, const int* in_sizes, int n_in,
                              void* d_out, int out_size, void* d_ws, size_t ws_size,
                              hipStream_t stream)
{
    (void)in_sizes; (void)n_in; (void)out_size; (void)ws_size;
    const float* x  = (const float*)d_in[0];
    const float* Wq = (const float*)d_in[1];
    const float* Wk = (const float*)d_in[2];
    const float* Wv = (const float*)d_in[3];
    const float* Wo = (const float*)d_in[4];

    float* out0 = (float*)d_out;                  // [2,2048,2048]
    float* outk = out0 + 8388608;                 // [2,4,2048,128]
    float* outv = out0 + 10485760;                // [2,4,2048,128]

    __hip_bfloat16* wsb    = (__hip_bfloat16*)d_ws;
    __hip_bfloat16* xb     = wsb;                   //  8,388,608  [4096][2048]
    __hip_bfloat16* WqkvT  = xb + 8388608;          //  6,291,456  [3072][2048]
    __hip_bfloat16* WoT    = WqkvT + 6291456;       //  4,194,304  [2048][2048]
    __hip_bfloat16* qkv    = WoT + 4194304;         // 12,582,912  [4096][3072]
    __hip_bfloat16* VT     = qkv + 12582912;        //  2,097,152  [8][128][2048]
    __hip_bfloat16* attn_o = xb;                    // alias: xb dead after QKV GEMM

    prep_kernel<<<dim3(288, 64), dim3(32, 8), 0, stream>>>(
        x, Wq, Wk, Wv, Wo, xb, WqkvT, WoT);

    gemm_qkv_fused<<<768, 256, 0, stream>>>(xb, WqkvT, qkv, outk, outv, VT);

    attn_kernel<<<dim3(32, 16), 256, 0, stream>>>(qkv, VT, attn_o);

    gemm_bt_kernel<float><<<512, 256, 0, stream>>>(attn_o, WoT, out0, 4096, 2048, 2048);
}

// Round 19
// 188.862 us; speedup vs baseline: 1.0445x; 1.0445x over previous
//
#include <hip/hip_runtime.h>
#include <hip/hip_bf16.h>
#include <type_traits>

// Problem: B=2, T=2048, D_MODEL=2048, H=16, Hkv=4, hd=128.
// Outputs (fp32, concat): out[2,2048,2048] | k_roped[2,4,2048,128] | v[2,4,2048,128]
//
// Q/K columns inside the internal qkv buffer are stored PERMUTED (per-head
// 32-col blocks [0,2,1,3]) so the RoPE pair (d, d+64) = stored (c, c+32).
// QK^T is permutation-invariant (both sides permuted), attention unchanged.

typedef short  short8 __attribute__((ext_vector_type(8)));
typedef float  f32x4  __attribute__((ext_vector_type(4)));
typedef float  f32x16 __attribute__((ext_vector_type(16)));

#define AS1(p) ((__attribute__((address_space(1))) void*)(p))
#define AS3(p) ((__attribute__((address_space(3))) void*)(p))

static __device__ inline short bf_bits(float f) {
    __hip_bfloat16 h = __float2bfloat16(f);
    return *reinterpret_cast<short*>(&h);
}

// ---------------- Fused prep: weight transposes + x conversion ----------------
__global__ void prep_kernel(
    const float* __restrict__ x,
    const float* __restrict__ Wq, const float* __restrict__ Wk,
    const float* __restrict__ Wv, const float* __restrict__ Wo,
    __hip_bfloat16* __restrict__ xb,
    __hip_bfloat16* __restrict__ WqkvT, __hip_bfloat16* __restrict__ WoT)
{
    const int nb = blockIdx.x;
    const int tx = threadIdx.x, ty = threadIdx.y;   // 32 x 8
    if (nb >= 160) {
        int bid2 = (nb - 160) * 64 + blockIdx.y;    // 0..8191
        int i = (bid2 * 256 + ty * 32 + tx) * 4;
        float4 v = *reinterpret_cast<const float4*>(x + i);
        ushort4 o;
        o.x = (unsigned short)bf_bits(v.x);
        o.y = (unsigned short)bf_bits(v.y);
        o.z = (unsigned short)bf_bits(v.z);
        o.w = (unsigned short)bf_bits(v.w);
        *reinterpret_cast<ushort4*>(reinterpret_cast<unsigned short*>(xb) + i) = o;
        return;
    }
    __shared__ float tile[32][33];
    const int k0 = blockIdx.y * 32;
    const float* W; int srcN, sn0, drow; __hip_bfloat16* dst;
    if (nb < 64) {
        int blk = nb & 3;
        int blk2 = ((blk & 1) << 1) | (blk >> 1);   // 0,2,1,3
        W = Wq; srcN = 2048; sn0 = nb * 32;
        dst = WqkvT; drow = ((nb >> 2) * 4 + blk2) * 32;
    } else if (nb < 80) {
        int i = nb - 64, blk = i & 3;
        int blk2 = ((blk & 1) << 1) | (blk >> 1);
        W = Wk; srcN = 512; sn0 = i * 32;
        dst = WqkvT; drow = 2048 + ((i >> 2) * 4 + blk2) * 32;
    } else if (nb < 96) {
        int i = nb - 80;
        W = Wv; srcN = 512; sn0 = i * 32;
        dst = WqkvT; drow = 2560 + i * 32;
    } else {
        int i = nb - 96;
        W = Wo; srcN = 2048; sn0 = i * 32;
        dst = WoT; drow = i * 32;
    }
#pragma unroll
    for (int i = 0; i < 32; i += 8)
        tile[ty + i][tx] = W[(size_t)(k0 + ty + i) * srcN + sn0 + tx];
    __syncthreads();
#pragma unroll
    for (int i = 0; i < 32; i += 8)
        dst[(size_t)(drow + ty + i) * 2048 + k0 + tx] = __float2bfloat16(tile[tx][ty + i]);
}

// XCD-aware block decode for 128^2 tiles.
static __device__ inline void xcd_decode(int bid, int M, int N, int& m0, int& n0)
{
    const int xcd = bid & 7;
    const int idx = bid >> 3;
    const int mpx = (M >> 7) >> 3;
    const int rem = idx % (mpx * 4);
    const int mb = xcd * mpx + rem % mpx;
    const int nb = (idx / (mpx * 4)) * 4 + rem / mpx;
    m0 = mb << 7;
    n0 = nb << 7;
}

// Counted waits (T4): never drain to 0 in the main loop.
#define WAITV4 asm volatile("s_waitcnt vmcnt(4)" ::: "memory")
#define WAITV0 asm volatile("s_waitcnt vmcnt(0)" ::: "memory")

// ---------------- Wo GEMM: C[M][N] = A[M][K] * BT[N][K]^T ----------------
// 128x128 tile, 4 waves (2x2 of 64x64), BK=64, 2-phase double-buffered LDS,
// XOR-swizzled staging, 32x32x16 MFMA, XCD decode, T5 setprio on MFMA.
template <typename CT>
__global__ __launch_bounds__(256) void gemm_bt_kernel(
    const __hip_bfloat16* __restrict__ A,
    const __hip_bfloat16* __restrict__ BT,
    CT* __restrict__ C, int M, int N, int K)
{
    const int tid  = threadIdx.x;
    const int w    = tid >> 6;
    const int lane = tid & 63;
    const int l31  = lane & 31;
    const int hi   = lane >> 5;
    int m0, n0;
    xcd_decode(blockIdx.x, M, N, m0, n0);
    const int wm = (w >> 1) << 6;
    const int wn = (w & 1) << 6;

    __shared__ __hip_bfloat16 As[2][128 * 64];   // 32 KB
    __shared__ __hip_bfloat16 Bs[2][128 * 64];   // 32 KB

    f32x16 acc[2][2] = {};

#define GSTAGE(buf, k0_)                                                            \
    {                                                                               \
        _Pragma("unroll")                                                           \
        for (int i = 0; i < 4; ++i) {                                               \
            int c = tid + i * 256;                                                  \
            int row = c >> 3;                                                       \
            int soct = (c & 7) ^ (row & 7);                                         \
            const __hip_bfloat16* ga = A  + (size_t)(m0 + row) * K + (k0_) + soct * 8; \
            const __hip_bfloat16* gb = BT + (size_t)(n0 + row) * K + (k0_) + soct * 8; \
            __builtin_amdgcn_global_load_lds(AS1(ga), AS3(&As[buf][c * 8]), 16, 0, 0); \
            __builtin_amdgcn_global_load_lds(AS1(gb), AS3(&Bs[buf][c * 8]), 16, 0, 0); \
        }                                                                           \
    }

    GSTAGE(0, 0);
    __syncthreads();
    int cur = 0;
    const int nk = K >> 6;

    for (int t = 0; t < nk; ++t) {
        if (t + 1 < nk) GSTAGE(cur ^ 1, (t + 1) << 6);

        __builtin_amdgcn_s_setprio(1);
#pragma unroll
        for (int ks = 0; ks < 4; ++ks) {
            const int oct = ((ks * 2 + hi) ^ (l31 & 7)) << 3;
            short8 a[2], b[2];
#pragma unroll
            for (int mi = 0; mi < 2; ++mi)
                a[mi] = *reinterpret_cast<const short8*>(
                    reinterpret_cast<const short*>(&As[cur][0]) + (wm + mi * 32 + l31) * 64 + oct);
#pragma unroll
            for (int ni = 0; ni < 2; ++ni)
                b[ni] = *reinterpret_cast<const short8*>(
                    reinterpret_cast<const short*>(&Bs[cur][0]) + (wn + ni * 32 + l31) * 64 + oct);
#pragma unroll
            for (int mi = 0; mi < 2; ++mi)
#pragma unroll
                for (int ni = 0; ni < 2; ++ni)
                    acc[mi][ni] = __builtin_amdgcn_mfma_f32_32x32x16_bf16(
                        a[mi], b[ni], acc[mi][ni], 0, 0, 0);
        }
        __builtin_amdgcn_s_setprio(0);
        __syncthreads();
        cur ^= 1;
    }
#undef GSTAGE

#pragma unroll
    for (int mi = 0; mi < 2; ++mi)
#pragma unroll
        for (int ni = 0; ni < 2; ++ni)
#pragma unroll
            for (int reg = 0; reg < 16; ++reg) {
                int row = m0 + wm + mi * 32 + (reg & 3) + 8 * (reg >> 2) + 4 * hi;
                int col = n0 + wn + ni * 32 + l31;
                float v = acc[mi][ni][reg];
                if constexpr (std::is_same<CT, float>::value)
                    C[(size_t)row * N + col] = v;
                else
                    C[(size_t)row * N + col] = __float2bfloat16(v);
            }
}

// ---------------- Fused QKV GEMM + RoPE + K/V write-out ----------------
// R12-proven: ring-3/BK=32/counted-vmcnt, 128^2 tile, 2x2 wave layout,
// T5 setprio around the ds_read+MFMA cluster.
__global__ __launch_bounds__(256) void gemm_qkv_fused(
    const __hip_bfloat16* __restrict__ A,    // xb [4096][2048]
    const __hip_bfloat16* __restrict__ BT,   // WqkvT [3072][2048] (Q/K perm)
    __hip_bfloat16* __restrict__ qkv,        // [4096][3072]
    float* __restrict__ outk,                // [2,4,2048,128]
    float* __restrict__ outv,                // [2,4,2048,128]
    __hip_bfloat16* __restrict__ VT)         // [8][128][2048]
{
    const int tid  = threadIdx.x;
    const int w    = tid >> 6;
    const int lane = tid & 63;
    const int l31  = lane & 31;
    const int hi   = lane >> 5;
    int m0, n0;
    xcd_decode(blockIdx.x, 4096, 3072, m0, n0);
    const int wm = (w >> 1) << 6;            // 2x2 waves of 64x64
    const int wn = (w & 1) << 6;
    const int K = 2048;

    __shared__ __hip_bfloat16 As[3][128 * 32];
    __shared__ __hip_bfloat16 Bs[3][128 * 32];

    f32x16 acc[2][2] = {};

#define GSTAGE(buf, k0_)                                                             \
    {                                                                                \
        _Pragma("unroll")                                                            \
        for (int i = 0; i < 2; ++i) {                                                \
            int c = tid + i * 256;                                                   \
            int row = c >> 2;                                                        \
            int soct = (c & 3) ^ ((row >> 1) & 3);                                   \
            const __hip_bfloat16* ga = A  + (size_t)(m0 + row) * K + (k0_) + soct * 8; \
            const __hip_bfloat16* gb = BT + (size_t)(n0 + row) * K + (k0_) + soct * 8; \
            __builtin_amdgcn_global_load_lds(AS1(ga), AS3(&As[buf][c * 8]), 16, 0, 0); \
            __builtin_amdgcn_global_load_lds(AS1(gb), AS3(&Bs[buf][c * 8]), 16, 0, 0); \
        }                                                                            \
    }

    const int nk = 64;
    GSTAGE(0, 0);
    GSTAGE(1, 32);
    int cur = 0, stg = 2;

    for (int t = 0; t < nk; ++t) {
        if (t == nk - 1) { WAITV0; } else { WAITV4; }
        __builtin_amdgcn_s_barrier();
        __builtin_amdgcn_sched_barrier(0);
        if (t + 2 < nk) GSTAGE(stg, (t + 2) << 5);

        __builtin_amdgcn_s_setprio(1);
#pragma unroll
        for (int ks = 0; ks < 2; ++ks) {
            short8 a[2], b[2];
#pragma unroll
            for (int mi = 0; mi < 2; ++mi) {
                int row = wm + mi * 32 + l31;
                a[mi] = *reinterpret_cast<const short8*>(
                    reinterpret_cast<const short*>(&As[cur][0])
                    + row * 32 + (((ks * 2 + hi) ^ ((row >> 1) & 3)) << 3));
            }
#pragma unroll
            for (int ni = 0; ni < 2; ++ni) {
                int row = wn + ni * 32 + l31;
                b[ni] = *reinterpret_cast<const short8*>(
                    reinterpret_cast<const short*>(&Bs[cur][0])
                    + row * 32 + (((ks * 2 + hi) ^ ((row >> 1) & 3)) << 3));
            }
#pragma unroll
            for (int mi = 0; mi < 2; ++mi)
#pragma unroll
                for (int ni = 0; ni < 2; ++ni)
                    acc[mi][ni] = __builtin_amdgcn_mfma_f32_32x32x16_bf16(
                        a[mi], b[ni], acc[mi][ni], 0, 0, 0);
        }
        __builtin_amdgcn_s_setprio(0);
        cur = (cur == 2) ? 0 : cur + 1;
        stg = (stg == 2) ? 0 : stg + 1;
    }
#undef GSTAGE

    const int hc = n0 >> 7;                  // head-chunk 0..23
    if (hc < 20) {
        const int c0 = wn + l31;
        const int d_lo = (wn ? 32 : 0) + l31;
        const float invf = exp2f((float)d_lo * -0.20762050593046f);
        const int kh = hc - 16;
#pragma unroll
        for (int mi = 0; mi < 2; ++mi)
#pragma unroll
            for (int reg = 0; reg < 16; ++reg) {
                int row = m0 + wm + mi * 32 + (reg & 3) + 8 * (reg >> 2) + 4 * hi;
                int b = row >> 11, t = row & 2047;
                float ang = (float)t * invf;
                float s = __sinf(ang), c = __cosf(ang);
                float x1 = acc[mi][0][reg], x2 = acc[mi][1][reg];
                float o1 = x1 * c - x2 * s;
                float o2 = x2 * c + x1 * s;
                __hip_bfloat16* q = qkv + (size_t)row * 3072 + hc * 128 + c0;
                q[0]  = __float2bfloat16(o1);
                q[32] = __float2bfloat16(o2);
                if (hc >= 16) {
                    float* ok = outk + (size_t)((b * 4 + kh) * 2048 + t) * 128 + d_lo;
                    ok[0]  = o1;
                    ok[64] = o2;
                }
            }
    } else {
        const int kh = hc - 20;
#pragma unroll
        for (int mi = 0; mi < 2; ++mi)
#pragma unroll
            for (int reg = 0; reg < 16; ++reg) {
                int row = m0 + wm + mi * 32 + (reg & 3) + 8 * (reg >> 2) + 4 * hi;
                int b = row >> 11, t = row & 2047;
#pragma unroll
                for (int ni = 0; ni < 2; ++ni) {
                    int d = wn + ni * 32 + l31;
                    float v = acc[mi][ni][reg];
                    outv[(size_t)((b * 4 + kh) * 2048 + t) * 128 + d] = v;
                    VT[(size_t)((b * 4 + kh) * 128 + d) * 2048 + t] = __float2bfloat16(v);
                }
            }
    }
}

// ---------------- Flash attention v7 (causal, GQA) — R12/R16-proven ----------------
// 4 waves x 32 q-rows, KVBLK=64, double-buffered K/V via global_load_lds,
// swizzled, ones-MFMA row-sum, no max tracking, whole q-blocks, LPT pairing.
__global__ __launch_bounds__(256, 2) void attn_kernel(
    const __hip_bfloat16* __restrict__ qkv,
    const __hip_bfloat16* __restrict__ VT,
    __hip_bfloat16* __restrict__ outO)
{
    const int bh = blockIdx.x;          // b*16 + h
    const int b = bh >> 4, h = bh & 15;
    const int kh = h >> 2;
    const int yb = blockIdx.y;          // 0..15
    const int qblk = (yb < 8) ? (15 - yb) : (yb - 8);   // LPT: heavy blocks first
    const int tid = threadIdx.x;
    const int w = tid >> 6;
    const int lane = tid & 63;
    const int lo16 = lane & 15, grp = lane >> 4;
    const int qrow0 = qblk * 128 + w * 32;

    __shared__ short Ks[2][64 * 128];   // 32 KB  [key][d]   (swizzled octets)
    __shared__ short Vs[2][128 * 64];   // 32 KB  [d][key]   (swizzled octets)
    __shared__ short Ps[4][32 * 64];    // 16 KB  per-wave P (swizzled octets)

    const short* qkvs = reinterpret_cast<const short*>(qkv);
    const size_t kbase = (size_t)b * 2048 * 3072 + 2048 + kh * 128;
    const short* vtb = reinterpret_cast<const short*>(VT) + (size_t)(b * 4 + kh) * 128 * 2048;
    short* pw = &Ps[w][0];

    short8 qf[2][4];
#pragma unroll
    for (int mi = 0; mi < 2; ++mi) {
        const short* qp = qkvs + (size_t)(b * 2048 + qrow0 + mi * 16 + lo16) * 3072
                        + h * 128 + grp * 8;
#pragma unroll
        for (int ss = 0; ss < 4; ++ss)
            qf[mi][ss] = *reinterpret_cast<const short8*>(qp + ss * 32);
    }

    f32x4 o[2][8] = {};
    f32x4 lac[2] = {};

    short8 ones;
#pragma unroll
    for (int jj = 0; jj < 8; ++jj) ones[jj] = (short)0x3F80;   // bf16 1.0

    const float scl2 = 0.12752749545902973f;   // (1/sqrt(128)) * log2(e)
    const int ntiles = qblk * 2 + 2;

#define STAGE(buf, kb_)                                                              \
    {                                                                                \
        _Pragma("unroll")                                                            \
        for (int i = 0; i < 4; ++i) {                                                \
            int c = tid + i * 256;                                                   \
            int row = c >> 4, c16 = (c & 15) ^ (row & 7);                            \
            const short* src = qkvs + kbase + (size_t)((kb_) + row) * 3072 + c16 * 8;\
            __builtin_amdgcn_global_load_lds(AS1(src),                               \
                AS3(&Ks[buf][(w * 64 + i * 256) * 8]), 16, 0, 0);                    \
        }                                                                            \
        _Pragma("unroll")                                                            \
        for (int i = 0; i < 4; ++i) {                                                \
            int c = tid + i * 256;                                                   \
            int d = c >> 3, c8 = (c & 7) ^ (d & 7);                                  \
            const short* src = vtb + (size_t)d * 2048 + (kb_) + c8 * 8;              \
            __builtin_amdgcn_global_load_lds(AS1(src),                               \
                AS3(&Vs[buf][(w * 64 + i * 256) * 8]), 16, 0, 0);                    \
        }                                                                            \
    }

    STAGE(0, 0);
    __syncthreads();
    int cur = 0;

    for (int t = 0; t < ntiles; ++t) {
        const int kb = t * 64;
        if (t + 1 < ntiles) STAGE(cur ^ 1, kb + 64);

        f32x4 sg[2][4];
        __builtin_amdgcn_s_setprio(1);
#pragma unroll
        for (int kg = 0; kg < 4; ++kg) {
            f32x4 a0 = {}, a1 = {};
#pragma unroll
            for (int ss = 0; ss < 4; ++ss) {
                short8 kf = *reinterpret_cast<const short8*>(
                    &Ks[cur][(kg * 16 + lo16) * 128 + (((ss * 4 + grp) ^ (lo16 & 7)) << 3)]);
                a0 = __builtin_amdgcn_mfma_f32_16x16x32_bf16(qf[0][ss], kf, a0, 0, 0, 0);
                a1 = __builtin_amdgcn_mfma_f32_16x16x32_bf16(qf[1][ss], kf, a1, 0, 0, 0);
            }
            sg[0][kg] = a0; sg[1][kg] = a1;
        }
        __builtin_amdgcn_s_setprio(0);

        if (kb + 63 > qrow0) {
#pragma unroll
            for (int mi = 0; mi < 2; ++mi)
#pragma unroll
                for (int kg = 0; kg < 4; ++kg) {
                    const int key = kb + kg * 16 + lo16;
#pragma unroll
                    for (int r = 0; r < 4; ++r) {
                        float v = sg[mi][kg][r] * scl2;
                        sg[mi][kg][r] = (key <= qrow0 + mi * 16 + grp * 4 + r) ? v : -1e30f;
                    }
                }
        } else {
#pragma unroll
            for (int mi = 0; mi < 2; ++mi)
#pragma unroll
                for (int kg = 0; kg < 4; ++kg)
#pragma unroll
                    for (int r = 0; r < 4; ++r) sg[mi][kg][r] *= scl2;
        }

#pragma unroll
        for (int mi = 0; mi < 2; ++mi)
#pragma unroll
            for (int kg = 0; kg < 4; ++kg)
#pragma unroll
                for (int r = 0; r < 4; ++r) {
                    float p = __builtin_amdgcn_exp2f(sg[mi][kg][r]);
                    int row = mi * 16 + grp * 4 + r;
                    int idx = row * 64 + (((kg * 2 + (lo16 >> 3)) ^ (row & 7)) << 3) + (lo16 & 7);
                    pw[idx] = bf_bits(p);
                }

        __builtin_amdgcn_s_setprio(1);
#pragma unroll
        for (int ks = 0; ks < 2; ++ks) {
            short8 pf0 = *reinterpret_cast<const short8*>(
                &pw[(0 * 16 + lo16) * 64 + (((ks * 4 + grp) ^ (lo16 & 7)) << 3)]);
            short8 pf1 = *reinterpret_cast<const short8*>(
                &pw[(1 * 16 + lo16) * 64 + (((ks * 4 + grp) ^ (lo16 & 7)) << 3)]);
            lac[0] = __builtin_amdgcn_mfma_f32_16x16x32_bf16(pf0, ones, lac[0], 0, 0, 0);
            lac[1] = __builtin_amdgcn_mfma_f32_16x16x32_bf16(pf1, ones, lac[1], 0, 0, 0);
#pragma unroll
            for (int jj = 0; jj < 8; ++jj) {
                short8 vf = *reinterpret_cast<const short8*>(
                    &Vs[cur][(jj * 16 + lo16) * 64 + (((ks * 4 + grp) ^ (lo16 & 7)) << 3)]);
                o[0][jj] = __builtin_amdgcn_mfma_f32_16x16x32_bf16(pf0, vf, o[0][jj], 0, 0, 0);
                o[1][jj] = __builtin_amdgcn_mfma_f32_16x16x32_bf16(pf1, vf, o[1][jj], 0, 0, 0);
            }
        }
        __builtin_amdgcn_s_setprio(0);

        __syncthreads();
        cur ^= 1;
    }
#undef STAGE

#pragma unroll
    for (int mi = 0; mi < 2; ++mi)
#pragma unroll
        for (int r = 0; r < 4; ++r) {
            float inv = 1.0f / lac[mi][r];
#pragma unroll
            for (int jj = 0; jj < 8; ++jj) {
                outO[(size_t)(b * 2048 + qrow0 + mi * 16 + grp * 4 + r) * 2048
                     + h * 128 + jj * 16 + lo16] = __float2bfloat16(o[mi][jj][r] * inv);
            }
        }
}

extern "C" void kernel_launch(void* const* d_in, const int* in_sizes, int n_in,
                              void* d_out, int out_size, void* d_ws, size_t ws_size,
                              hipStream_t stream)
{
    (void)in_sizes; (void)n_in; (void)out_size; (void)ws_size;
    const float* x  = (const float*)d_in[0];
    const float* Wq = (const float*)d_in[1];
    const float* Wk = (const float*)d_in[2];
    const float* Wv = (const float*)d_in[3];
    const float* Wo = (const float*)d_in[4];

    float* out0 = (float*)d_out;                  // [2,2048,2048]
    float* outk = out0 + 8388608;                 // [2,4,2048,128]
    float* outv = out0 + 10485760;                // [2,4,2048,128]

    __hip_bfloat16* wsb    = (__hip_bfloat16*)d_ws;
    __hip_bfloat16* xb     = wsb;                   //  8,388,608  [4096][2048]
    __hip_bfloat16* WqkvT  = xb + 8388608;          //  6,291,456  [3072][2048]
    __hip_bfloat16* WoT    = WqkvT + 6291456;       //  4,194,304  [2048][2048]
    __hip_bfloat16* qkv    = WoT + 4194304;         // 12,582,912  [4096][3072]
    __hip_bfloat16* VT     = qkv + 12582912;        //  2,097,152  [8][128][2048]
    __hip_bfloat16* attn_o = xb;                    // alias: xb dead after QKV GEMM

    prep_kernel<<<dim3(288, 64), dim3(32, 8), 0, stream>>>(
        x, Wq, Wk, Wv, Wo, xb, WqkvT, WoT);

    gemm_qkv_fused<<<768, 256, 0, stream>>>(xb, WqkvT, qkv, outk, outv, VT);

    attn_kernel<<<dim3(32, 16), 256, 0, stream>>>(qkv, VT, attn_o);

    gemm_bt_kernel<float><<<512, 256, 0, stream>>>(attn_o, WoT, out0, 4096, 2048, 2048);
}